// Round 15
// baseline (157.053 us; speedup 1.0000x reference)
//
#include <hip/hip_runtime.h>
#include <math.h>

#define NTOT 131072
#define NSIG 64
#define SEGL 2048
#define NIN 256
#define NBLK 512

// ws layout (bytes):
//   [0, 524288)        y[131072] f32
//   [524288, 1048576)  w_all[64][2048] f32 (only [1024-D, 1024+min(D,1023)] written)
//   [1048576, 1048832) Dv[64] int
//   [1048832, 1048836) ctr (arrival counter; memsetAsync'd to 0 each launch)
// Truncation: taps beyond |d| = 12|sigma|+4 are exp(<-72) == 0 in f32 and
// Z >= 1 (peak tap exp(0)=1), so truncation error ~1e-28 absolute.

// ---------------------------------------------------------------------------
// Fused k_y+k_conv with device barrier (R14 structure) + ONE change:
// amdgpu_waves_per_eu(2,2). Theory: the scheduler's default max-occupancy
// target (8 waves/EU, small LDS) caps the VGPR budget at ~64; the fused
// kernel's phase-B live state costs SGPRs, forcing VGPR-addressed loads whose
// 16-deep clustering (~48 VGPRs) no longer fits -> serialized stream (the
// recurring VGPR=36 / ~0.5 TB/s pathology). Pinning 2 waves/EU raises the
// budget to 256 VGPRs so the load clustering survives. 2 blocks/CU keeps all
// 512 blocks co-resident for the arrival barrier (spin is iteration-capped:
// residency failure degrades to a wrong answer, never a hang).
// ---------------------------------------------------------------------------
__global__ __launch_bounds__(256)
__attribute__((amdgpu_waves_per_eu(2, 2)))
void k_all(
    const float* __restrict__ x,  const float* __restrict__ W1,
    const float* __restrict__ b1, const float* __restrict__ W2,
    const float* __restrict__ b2, const float* __restrict__ W3,
    const float* __restrict__ b3, float* __restrict__ y,
    float* __restrict__ w_all, int* __restrict__ Dv,
    unsigned int* __restrict__ ctr, float* __restrict__ out)
{
  __shared__ float xl[NIN];
  __shared__ float sl[256];
  __shared__ float red[4];
  __shared__ float bc[2];
  __shared__ float S[2560];   // phase B staging (seg coord = sbase + idx)

  const int t = threadIdx.x;
  const int bx0 = (int)blockIdx.x;
  // bijective XCD swizzle: 64 consecutive 256-col chunks per XCD
  const int bx = ((bx0 & 7) << 6) | (bx0 >> 3);
  const int col = (bx << 8) + t;

  xl[t] = x[t];
  __syncthreads();

  // ================= phase A: y = x@W3 + b3 (+ duty sigma/window) ==========
  const float* p = W3 + col;
  float a = b3[col];

  if (bx0 < NSIG) {
    // ---- duty block: matvec + MLP in one loop ----
    float am = b1[t];
    #pragma unroll 16
    for (int n = 0; n < NIN; ++n) {
      const float xv = xl[n];
      a  = fmaf(xv, __builtin_nontemporal_load(p + (size_t)n * NTOT), a);
      am = fmaf(xv, W1[n * 256 + t], am);
    }
    y[col] = a;
    sl[t] = am / (1.0f + expf(-am));
    __syncthreads();

    const int seg = bx0;
    float v = sl[t] * W2[t * NSIG + seg];
    #pragma unroll
    for (int o = 32; o > 0; o >>= 1) v += __shfl_down(v, o, 64);
    const int lane = t & 63, wid = t >> 6;
    if (lane == 0) red[wid] = v;
    __syncthreads();
    if (t == 0) bc[0] = red[0] + red[1] + red[2] + red[3] + b2[seg];
    __syncthreads();
    const float sig = bc[0];

    const float inv2 = 1.0f / (2.0f * sig * sig);
    const float Df = 12.0f * fabsf(sig) + 4.0f;
    const int D = (Df >= 1024.0f) ? 1024 : (int)Df;
    const int dlo = -D;
    const int dhi = (D < 1023) ? D : 1023;
    const int cnt = dhi - dlo + 1;

    float zp = 0.0f;
    for (int i = t; i < cnt; i += 256) {
      const float d = (float)(dlo + i);
      const float e = expf(-d * d * inv2);
      w_all[seg * SEGL + 1024 + dlo + i] = e;
      zp += e;
    }
    v = zp;
    #pragma unroll
    for (int o = 32; o > 0; o >>= 1) v += __shfl_down(v, o, 64);
    if (lane == 0) red[wid] = v;
    __syncthreads();
    if (t == 0) bc[1] = red[0] + red[1] + red[2] + red[3];
    __syncthreads();
    const float iZ = 1.0f / bc[1];
    for (int i = t; i < cnt; i += 256)
      w_all[seg * SEGL + 1024 + dlo + i] *= iZ;
    if (t == 0) Dv[seg] = D;
  } else {
    // ---- pure stream ----
    #pragma unroll 16
    for (int n = 0; n < NIN; ++n)
      a = fmaf(xl[n], __builtin_nontemporal_load(p + (size_t)n * NTOT), a);
    y[col] = a;
  }

  // ================= device barrier ========================================
  __syncthreads();          // all waves of this block done with phase A
  __threadfence();          // y / w_all / Dv globally visible (device scope)
  if (t == 0) {
    atomicAdd(ctr, 1u);
    int it = 0;
    while (__hip_atomic_load(ctr, __ATOMIC_RELAXED, __HIP_MEMORY_SCOPE_AGENT)
               < (unsigned)NBLK && it < (1 << 20)) {
      __builtin_amdgcn_s_sleep(2);
      ++it;
    }
  }
  __syncthreads();
  __threadfence();          // acquire side

  // ================= phase B: truncated conv (k_conv verbatim) ============
  const int segc = bx >> 3;
  const int M0 = (bx & 7) << 8;
  const int sbase = M0 - 1026;

  const int D = Dv[segc];
  const int dlo = -D;
  const int dhi = (D < 1023) ? D : 1023;

  // live span of S: [1025-dhi, 1281+D)
  const int ilo = 1025 - dhi;
  const int ihi = 1281 + D;
  for (int i = ilo + t; i < ihi; i += 256) {
    const int g = sbase + i;
    S[i] = (g >= 0 && g < SEGL) ? y[segc * SEGL + g] : 0.0f;
  }
  __syncthreads();

  const float* wrow = w_all + segc * SEGL + 1024;
  float acc = 0.0f;
  for (int d = dlo; d <= dhi; ++d)
    acc = fmaf(wrow[d], S[t + 1025 - d], acc);   // wrow[d] block-uniform
  out[segc * SEGL + M0 + t] = acc;
}

// ---------------------------------------------------------------------------
extern "C" void kernel_launch(void* const* d_in, const int* in_sizes, int n_in,
                              void* d_out, int out_size, void* d_ws, size_t ws_size,
                              hipStream_t stream) {
  const float* x  = (const float*)d_in[0];
  const float* W1 = (const float*)d_in[1];
  const float* b1 = (const float*)d_in[2];
  const float* W2 = (const float*)d_in[3];
  const float* b2 = (const float*)d_in[4];
  const float* W3 = (const float*)d_in[5];
  const float* b3 = (const float*)d_in[6];
  float* out = (float*)d_out;

  char* ws = (char*)d_ws;
  float* y     = (float*)(ws);
  float* w_all = (float*)(ws + 524288);
  int*   Dv    = (int*)  (ws + 1048576);
  unsigned int* ctr = (unsigned int*)(ws + 1048832);

  hipMemsetAsync(ctr, 0, 4, stream);   // capture-legal async memset
  hipLaunchKernelGGL(k_all, dim3(NBLK), dim3(256), 0, stream,
                     x, W1, b1, W2, b2, W3, b3, y, w_all, Dv, ctr, out);
}

// Round 16
// 31.518 us; speedup vs baseline: 4.9830x; 4.9830x over previous
//
#include <hip/hip_runtime.h>
#include <math.h>

#define NTOT 131072
#define NSIG 64
#define SEGL 2048
#define NIN 256

// ws layout (bytes):
//   [0, 524288)        y[131072] f32
//   [524288, 1048576)  w_all[64][2048] f32 (only [1024-D, 1024+min(D,1023)] written)
//   [1048576, 1048832) Dv[64] int
// Truncation: taps beyond |d| = 12|sigma|+4 are exp(<-72) == 0 in f32 and
// Z >= 1 (peak tap exp(0)=1), so truncation error ~1e-28 absolute.

// ---------------------------------------------------------------------------
// K1: y = x@W3 + b3 (measured-best structure, R13 verbatim): 512 blocks x
// 256 threads, 2 blocks/CU, 8 waves/CU, thread-per-column scalar unroll-16,
// branch-free, __builtin_nontemporal_load on the zero-reuse W3 stream.
// Duty blocks (bx0 < 64) fold the MLP dot into the same loop, then
// sigma -> truncated normalized window for segment bx0.
// ---------------------------------------------------------------------------
__global__ __launch_bounds__(256) void k_y(
    const float* __restrict__ x,  const float* __restrict__ W1,
    const float* __restrict__ b1, const float* __restrict__ W2,
    const float* __restrict__ b2, const float* __restrict__ W3,
    const float* __restrict__ b3, float* __restrict__ y,
    float* __restrict__ w_all, int* __restrict__ Dv)
{
  __shared__ float xl[NIN];
  __shared__ float sl[256];
  __shared__ float red[4];
  __shared__ float bc[2];

  const int t = threadIdx.x;
  const int bx0 = (int)blockIdx.x;
  // bijective XCD swizzle: 64 consecutive 256-col chunks per XCD
  const int bx = ((bx0 & 7) << 6) | (bx0 >> 3);
  const int col = (bx << 8) + t;

  xl[t] = x[t];
  __syncthreads();

  const float* p = W3 + col;
  float a = b3[col];

  if (bx0 < NSIG) {
    // ---- duty block: matvec + MLP in one loop ----
    float am = b1[t];
    #pragma unroll 16
    for (int n = 0; n < NIN; ++n) {
      const float xv = xl[n];
      a  = fmaf(xv, __builtin_nontemporal_load(p + (size_t)n * NTOT), a);
      am = fmaf(xv, W1[n * 256 + t], am);
    }
    y[col] = a;
    sl[t] = am / (1.0f + expf(-am));
    __syncthreads();

    const int seg = bx0;
    float v = sl[t] * W2[t * NSIG + seg];
    #pragma unroll
    for (int o = 32; o > 0; o >>= 1) v += __shfl_down(v, o, 64);
    const int lane = t & 63, wid = t >> 6;
    if (lane == 0) red[wid] = v;
    __syncthreads();
    if (t == 0) bc[0] = red[0] + red[1] + red[2] + red[3] + b2[seg];
    __syncthreads();
    const float sig = bc[0];

    const float inv2 = 1.0f / (2.0f * sig * sig);
    const float Df = 12.0f * fabsf(sig) + 4.0f;
    const int D = (Df >= 1024.0f) ? 1024 : (int)Df;
    const int dlo = -D;
    const int dhi = (D < 1023) ? D : 1023;
    const int cnt = dhi - dlo + 1;

    float zp = 0.0f;
    for (int i = t; i < cnt; i += 256) {
      const float d = (float)(dlo + i);
      const float e = expf(-d * d * inv2);
      w_all[seg * SEGL + 1024 + dlo + i] = e;
      zp += e;
    }
    v = zp;
    #pragma unroll
    for (int o = 32; o > 0; o >>= 1) v += __shfl_down(v, o, 64);
    if (lane == 0) red[wid] = v;
    __syncthreads();
    if (t == 0) bc[1] = red[0] + red[1] + red[2] + red[3];
    __syncthreads();
    const float iZ = 1.0f / bc[1];
    for (int i = t; i < cnt; i += 256)
      w_all[seg * SEGL + 1024 + dlo + i] *= iZ;
    if (t == 0) Dv[seg] = D;
  } else {
    // ---- pure stream ----
    #pragma unroll 16
    for (int n = 0; n < NIN; ++n)
      a = fmaf(xl[n], __builtin_nontemporal_load(p + (size_t)n * NTOT), a);
    y[col] = a;
  }
}

// ---------------------------------------------------------------------------
// K2: truncated "same" conv (verbatim from the 31.2us-best config).
// 512 blocks x 256 threads; block bx handles [seg*2048 + M0, +256).
// Stages only the live y span; window read directly (block-uniform scalar).
// out[m] = sum_d w[1024+d] * seg[m-1-d], d in [-D, min(D,1023)]
// ---------------------------------------------------------------------------
__global__ __launch_bounds__(256) void k_conv(
    const float* __restrict__ y, const float* __restrict__ w_all,
    const int* __restrict__ Dv, float* __restrict__ out)
{
  __shared__ float S[2560];   // seg coord = sbase + idx

  const int t = threadIdx.x;
  const int bx0 = (int)blockIdx.x;
  const int bx = ((bx0 & 7) << 6) | (bx0 >> 3);   // same XCD as producer
  const int seg = bx >> 3;
  const int M0 = (bx & 7) << 8;
  const int sbase = M0 - 1026;

  const int D = Dv[seg];
  const int dlo = -D;
  const int dhi = (D < 1023) ? D : 1023;

  // live span of S: [1025-dhi, 1281+D)
  const int ilo = 1025 - dhi;
  const int ihi = 1281 + D;
  for (int i = ilo + t; i < ihi; i += 256) {
    const int g = sbase + i;
    S[i] = (g >= 0 && g < SEGL) ? y[seg * SEGL + g] : 0.0f;
  }
  __syncthreads();

  const float* wrow = w_all + seg * SEGL + 1024;
  float a = 0.0f;
  for (int d = dlo; d <= dhi; ++d)
    a = fmaf(wrow[d], S[t + 1025 - d], a);   // wrow[d] block-uniform
  out[seg * SEGL + M0 + t] = a;
}

// ---------------------------------------------------------------------------
extern "C" void kernel_launch(void* const* d_in, const int* in_sizes, int n_in,
                              void* d_out, int out_size, void* d_ws, size_t ws_size,
                              hipStream_t stream) {
  const float* x  = (const float*)d_in[0];
  const float* W1 = (const float*)d_in[1];
  const float* b1 = (const float*)d_in[2];
  const float* W2 = (const float*)d_in[3];
  const float* b2 = (const float*)d_in[4];
  const float* W3 = (const float*)d_in[5];
  const float* b3 = (const float*)d_in[6];
  float* out = (float*)d_out;

  char* ws = (char*)d_ws;
  float* y     = (float*)(ws);
  float* w_all = (float*)(ws + 524288);
  int*   Dv    = (int*)  (ws + 1048576);

  hipLaunchKernelGGL(k_y, dim3(512), dim3(256), 0, stream,
                     x, W1, b1, W2, b2, W3, b3, y, w_all, Dv);
  hipLaunchKernelGGL(k_conv, dim3(512), dim3(256), 0, stream,
                     y, w_all, Dv, out);
}